// Round 10
// baseline (839.860 us; speedup 1.0000x reference)
//
#include <hip/hip_runtime.h>

#define NN 100000
#define DEG 16
#define HEADS 4
#define NEG_SLOPE 0.2f
#define NPAD 100096   // 782 * 128

typedef unsigned short ushort_t;
typedef __attribute__((ext_vector_type(8))) short bf16x8;
typedef __attribute__((ext_vector_type(4))) float f32x4;

__device__ __forceinline__ ushort_t f2bf_rn(float f) {
    uint32_t u = __float_as_uint(f);
    uint32_t r = (u + 0x7fffu + ((u >> 16) & 1u)) >> 16;
    return (ushort_t)r;
}
__device__ __forceinline__ float bf2f(ushort_t u) {
    return __uint_as_float(((uint32_t)u) << 16);
}

// async 16B global->LDS DMA: LDS dest = wave-uniform base + lane*16
__device__ __forceinline__ void gld16(const void* g, void* l) {
    __builtin_amdgcn_global_load_lds(
        (const __attribute__((address_space(1))) unsigned int*)g,
        (__attribute__((address_space(3))) unsigned int*)l, 16, 0, 0);
}

// ---- prep: W[k][col] -> fragment-linear hi/lo bf16 panels ------------------
__global__ __launch_bounds__(256) void prep_wt(
    const float* __restrict__ W, ushort_t* __restrict__ Wh,
    ushort_t* __restrict__ Wl, int ncr)
{
    int idx = blockIdx.x * 256 + threadIdx.x;   // 65536 elements
    int j     = idx & 7;
    int chunk = idx >> 3;
    int ln   = chunk & 63;
    int nf   = (chunk >> 6) & 3;
    int ksub = (chunk >> 8) & 1;
    int wn   = (chunk >> 9) & 1;
    int k0g  = (chunk >> 10) & 3;
    int p    = (chunk >> 12) & 1;
    int col = p * 128 + wn * 64 + nf * 16 + (ln & 15);
    int k   = k0g * 64 + ksub * 32 + (ln >> 4) * 8 + j;
    float v = (col < ncr) ? W[k * ncr + col] : 0.f;
    uint32_t b  = __float_as_uint(v);
    uint32_t hb = b & 0xffff0000u;
    float r = v - __uint_as_float(hb);
    Wh[idx] = (ushort_t)(hb >> 16);
    Wl[idx] = (ushort_t)(__float_as_uint(r) >> 16);
}

// ---- split-bf16 MFMA GEMM: C[M,256] = A[M,256] * W[256,256] ----------------
// AMODE 0: A = fp32 A32 (layer 0).  AMODE 1: presplit bf16 via gload_lds.
// Linear bf16 C epilogue (R7 codegen); DO_SCORES fuses el/er from fp32 acc.
template <int AMODE, bool DO_SCORES>
__global__ __launch_bounds__(256) void gemm_mfma(
    const float* __restrict__ A32,
    const ushort_t* __restrict__ Ahi, const ushort_t* __restrict__ Alo,
    const ushort_t* __restrict__ Bth, const ushort_t* __restrict__ Btl,
    const float* __restrict__ al, const float* __restrict__ ar,
    ushort_t* __restrict__ Cb, int ldc, int ncr,
    float* __restrict__ el, float* __restrict__ er)
{
    __shared__ uint4 smem[2048];    // A: [0:1024) hi, [1024:2048) lo  (32 KB)
    __shared__ uint4 smemB[2048];   // B: [0:1024) hi, [1024:2048) lo  (32 KB)

    const int tid  = threadIdx.x;
    const int wv   = tid >> 6;
    const int ln   = tid & 63;
    const int wm   = wv >> 1;
    const int wn   = wv & 1;
    const int cl   = ln & 15;
    const int kq   = ln >> 4;
    const int row0 = blockIdx.y * 128;
    const int col0 = blockIdx.x * 128;

    const ushort_t* bH = Bth + (size_t)blockIdx.x * 4 * 8192;
    const ushort_t* bL = Btl + (size_t)blockIdx.x * 4 * 8192;

    f32x4 acc[4][4] = {};

    for (int k0g = 0; k0g < 4; ++k0g) {
        const int k0 = k0g * 64;
        if (k0) __syncthreads();

        {
            const ushort_t* rh = bH + k0g * 8192;
            const ushort_t* rl = bL + k0g * 8192;
            #pragma unroll
            for (int q = 0; q < 4; ++q) {
                int i = wv * 4 + q;
                gld16(rh + (size_t)(i * 64 + ln) * 8, (char*)smemB + i * 1024);
                gld16(rl + (size_t)(i * 64 + ln) * 8, (char*)smemB + 16384 + i * 1024);
            }
        }

        if (AMODE == 1) {
            const int rl8 = ln >> 3;
            const int c   = (ln & 7) ^ rl8;
            #pragma unroll
            for (int q = 0; q < 4; ++q) {
                int rb = wv * 4 + q;
                size_t g = (size_t)(row0 + rb * 8 + rl8) * 256 + k0 + c * 8;
                gld16(Ahi + g, (char*)smem + rb * 1024);
                gld16(Alo + g, (char*)smem + 16384 + rb * 1024);
            }
        } else {
            #pragma unroll
            for (int p = 0; p < 4; ++p) {
                int s = p * 256 + tid;
                int row = s >> 3, c = s & 7;
                int csw = c ^ (row & 7);
                int gr = row0 + row;
                float4 v0 = make_float4(0.f,0.f,0.f,0.f), v1 = v0;
                if (gr < NN) {
                    const float* g = A32 + (size_t)gr * 256 + k0 + c * 8;
                    v0 = *reinterpret_cast<const float4*>(g);
                    v1 = *reinterpret_cast<const float4*>(g + 4);
                }
                uint32_t b0 = __float_as_uint(v0.x), b1 = __float_as_uint(v0.y);
                uint32_t b2 = __float_as_uint(v0.z), b3 = __float_as_uint(v0.w);
                uint32_t b4 = __float_as_uint(v1.x), b5 = __float_as_uint(v1.y);
                uint32_t b6 = __float_as_uint(v1.z), b7 = __float_as_uint(v1.w);
                uint4 vh;
                vh.x = (b1 & 0xffff0000u) | (b0 >> 16);
                vh.y = (b3 & 0xffff0000u) | (b2 >> 16);
                vh.z = (b5 & 0xffff0000u) | (b4 >> 16);
                vh.w = (b7 & 0xffff0000u) | (b6 >> 16);
                float r0 = v0.x - __uint_as_float(b0 & 0xffff0000u);
                float r1 = v0.y - __uint_as_float(b1 & 0xffff0000u);
                float r2 = v0.z - __uint_as_float(b2 & 0xffff0000u);
                float r3 = v0.w - __uint_as_float(b3 & 0xffff0000u);
                float r4 = v1.x - __uint_as_float(b4 & 0xffff0000u);
                float r5 = v1.y - __uint_as_float(b5 & 0xffff0000u);
                float r6 = v1.z - __uint_as_float(b6 & 0xffff0000u);
                float r7 = v1.w - __uint_as_float(b7 & 0xffff0000u);
                uint4 vl;
                vl.x = (__float_as_uint(r1) & 0xffff0000u) | (__float_as_uint(r0) >> 16);
                vl.y = (__float_as_uint(r3) & 0xffff0000u) | (__float_as_uint(r2) >> 16);
                vl.z = (__float_as_uint(r5) & 0xffff0000u) | (__float_as_uint(r4) >> 16);
                vl.w = (__float_as_uint(r7) & 0xffff0000u) | (__float_as_uint(r6) >> 16);
                smem[row * 8 + csw]        = vh;
                smem[1024 + row * 8 + csw] = vl;
            }
        }
        __syncthreads();

        #pragma unroll
        for (int ksub = 0; ksub < 2; ++ksub) {
            bf16x8 ah[4], ax[4];
            #pragma unroll
            for (int mf = 0; mf < 4; ++mf) {
                int row = wm * 64 + mf * 16 + cl;
                int chunk = (ksub * 4 + kq) ^ (row & 7);
                int idx = row * 8 + chunk;
                ah[mf] = ((const bf16x8*)smem)[idx];
                ax[mf] = ((const bf16x8*)smem)[1024 + idx];
            }
            #pragma unroll
            for (int nf = 0; nf < 4; ++nf) {
                int bidx = ((wn * 2 + ksub) * 4 + nf) * 64 + ln;
                bf16x8 bh = ((const bf16x8*)smemB)[bidx];
                bf16x8 bl = ((const bf16x8*)smemB)[1024 + bidx];
                #pragma unroll
                for (int mf = 0; mf < 4; ++mf) {
                    acc[mf][nf] = __builtin_amdgcn_mfma_f32_16x16x32_bf16(ah[mf], bh, acc[mf][nf], 0, 0, 0);
                    acc[mf][nf] = __builtin_amdgcn_mfma_f32_16x16x32_bf16(ah[mf], bl, acc[mf][nf], 0, 0, 0);
                    acc[mf][nf] = __builtin_amdgcn_mfma_f32_16x16x32_bf16(ax[mf], bh, acc[mf][nf], 0, 0, 0);
                }
            }
        }
    }

    // ---- epilogue: linear bf16 C store (+ fused scores) ------------------
    #pragma unroll
    for (int mf = 0; mf < 4; ++mf) {
        int gr0 = row0 + wm * 64 + mf * 16 + kq * 4;
        #pragma unroll
        for (int r = 0; r < 4; ++r) {
            int gr = gr0 + r;
            if (gr < NN) {
                #pragma unroll
                for (int nf = 0; nf < 4; ++nf) {
                    int gc = col0 + wn * 64 + nf * 16 + cl;
                    if (gc < ncr)
                        Cb[(size_t)gr * ldc + gc] = f2bf_rn(acc[mf][nf][r]);
                }
            }
        }
    }

    if (DO_SCORES) {
        const int head = blockIdx.x * 2 + wn;
        float alv[4], arv[4];
        #pragma unroll
        for (int nf = 0; nf < 4; ++nf) {
            int d = nf * 16 + cl;
            alv[nf] = al[head * 64 + d];
            arv[nf] = ar[head * 64 + d];
        }
        #pragma unroll
        for (int mf = 0; mf < 4; ++mf) {
            #pragma unroll
            for (int r = 0; r < 4; ++r) {
                float pl = 0.f, pr = 0.f;
                #pragma unroll
                for (int nf = 0; nf < 4; ++nf) {
                    pl += acc[mf][nf][r] * alv[nf];
                    pr += acc[mf][nf][r] * arv[nf];
                }
                #pragma unroll
                for (int msk = 1; msk <= 8; msk <<= 1) {
                    pl += __shfl_xor(pl, msk);
                    pr += __shfl_xor(pr, msk);
                }
                if (cl == 0) {
                    int gr = row0 + wm * 64 + mf * 16 + kq * 4 + r;
                    if (gr < NN) {
                        el[gr * HEADS + head] = pl;
                        er[gr * HEADS + head] = pr;
                    }
                }
            }
        }
    }
}

// ---- alpha_prep: softmax -> packed (src<<15 | alpha_q15) per (node,head,k) -
__global__ __launch_bounds__(256) void alpha_prep(
    const float* __restrict__ el, const float* __restrict__ er,
    const int* __restrict__ col, uint32_t* __restrict__ srcalpha)
{
    const int t = threadIdx.x;
    const int w = t >> 6;
    const int l = t & 63;
    const int n = blockIdx.x * 4 + w;
    const int h = l >> 4;
    const int k = l & 15;

    const int src = col[n * DEG + k];
    float x = el[src * HEADS + h] + er[n * HEADS + h];
    x = x > 0.f ? x : NEG_SLOPE * x;

    float m = x;
    #pragma unroll
    for (int msk = 8; msk >= 1; msk >>= 1) m = fmaxf(m, __shfl_xor(m, msk));
    float ex = __expf(x - m);
    float s = ex;
    #pragma unroll
    for (int msk = 8; msk >= 1; msk >>= 1) s += __shfl_xor(s, msk);

    uint32_t aq = (uint32_t)(ex / s * 32767.f + 0.5f);
    if (aq > 32767u) aq = 32767u;
    srcalpha[(size_t)n * 64 + l] = ((uint32_t)src << 15) | aq;
}

// ---- agg with XCD slice ownership over LINEAR featb (layers 0/1) -----------
// slice = bid&7 -> XCD s only touches byte-columns [64s,64s+64) of each row:
// each 64B chunk is exactly one aligned cache line -> disjoint line sets.
__global__ __launch_bounds__(256) void agg_sliced(
    const ushort_t* __restrict__ featb,     // [NN][256] linear
    const uint32_t* __restrict__ srcalpha,  // [N][4][16]
    ushort_t* __restrict__ Hhi, ushort_t* __restrict__ Hlo)
{
    __shared__ uint32_t s_pack[32][17];

    const int bid = blockIdx.x;
    const int s = bid & 7;          // slice / XCD
    const int g = bid >> 3;         // node group (32 nodes)
    const int t = threadIdx.x;
    const int nl = t >> 3;          // local node 0..31
    const int j  = t & 7;           // col chunk (4 cols)
    const int n  = g * 32 + nl;
    const int h  = s >> 1;          // head of this slice

    uint2 e2 = *reinterpret_cast<const uint2*>(
        &srcalpha[(size_t)n * 64 + h * 16 + j * 2]);
    s_pack[nl][j * 2]     = e2.x;
    s_pack[nl][j * 2 + 1] = e2.y;
    __syncthreads();

    const ushort_t* base = featb + s * 32 + j * 4;
    float4 acc = make_float4(0.f, 0.f, 0.f, 0.f);
    #pragma unroll
    for (int k = 0; k < DEG; ++k) {
        const uint32_t e = s_pack[nl][k];
        const float a = (float)(e & 0x7fffu) * (1.f / 32767.f);
        ushort4 f = *reinterpret_cast<const ushort4*>(&base[(size_t)(e >> 15) * 256]);
        acc.x += a * bf2f(f.x);
        acc.y += a * bf2f(f.y);
        acc.z += a * bf2f(f.z);
        acc.w += a * bf2f(f.w);
    }

    uint32_t bx = __float_as_uint(acc.x), by = __float_as_uint(acc.y);
    uint32_t bz = __float_as_uint(acc.z), bw = __float_as_uint(acc.w);
    ushort4 hv;
    hv.x = (ushort_t)(bx >> 16); hv.y = (ushort_t)(by >> 16);
    hv.z = (ushort_t)(bz >> 16); hv.w = (ushort_t)(bw >> 16);
    float rx = acc.x - __uint_as_float(bx & 0xffff0000u);
    float ry = acc.y - __uint_as_float(by & 0xffff0000u);
    float rz = acc.z - __uint_as_float(bz & 0xffff0000u);
    float rw = acc.w - __uint_as_float(bw & 0xffff0000u);
    ushort4 lv;
    lv.x = (ushort_t)(__float_as_uint(rx) >> 16);
    lv.y = (ushort_t)(__float_as_uint(ry) >> 16);
    lv.z = (ushort_t)(__float_as_uint(rz) >> 16);
    lv.w = (ushort_t)(__float_as_uint(rw) >> 16);
    const size_t o = (size_t)n * 256 + s * 32 + j * 4;
    *reinterpret_cast<ushort4*>(&Hhi[o]) = hv;
    *reinterpret_cast<ushort4*>(&Hlo[o]) = lv;
}

// ---- layer-2 scores from bf16 feat (D=41, HD=164) --------------------------
__global__ __launch_bounds__(256) void scores2_bf(
    const ushort_t* __restrict__ featb, const float* __restrict__ al,
    const float* __restrict__ ar, float* __restrict__ el, float* __restrict__ er)
{
    const int n = blockIdx.x;
    const int t = threadIdx.x;
    const int h = t >> 6;
    const int j = t & 63;
    float v = 0.f, u = 0.f;
    if (j < 41) {
        float f = bf2f(featb[(size_t)n * 164 + h * 41 + j]);
        v = f * al[h * 41 + j];
        u = f * ar[h * 41 + j];
    }
    #pragma unroll
    for (int off = 32; off > 0; off >>= 1) {
        v += __shfl_down(v, off);
        u += __shfl_down(u, off);
    }
    if (j == 0) {
        el[n * HEADS + h] = v;
        er[n * HEADS + h] = u;
    }
}

// ---- output-layer aggregation (HD=164, mean over heads) --------------------
__global__ __launch_bounds__(256) void agg_out_bf(
    const ushort_t* __restrict__ featb, const float* __restrict__ el,
    const float* __restrict__ er, const int* __restrict__ col,
    float* __restrict__ out)   // out: [N, 41]
{
    __shared__ int   s_src[4][DEG];
    __shared__ float s_alpha[4][HEADS][DEG];
    __shared__ float s_agg[4][164];

    const int t = threadIdx.x;
    const int w = t >> 6;
    const int l = t & 63;
    const int n = blockIdx.x * 4 + w;
    const int h = l >> 4;
    const int k = l & 15;

    const int src_k = col[n * DEG + k];
    float x = el[src_k * HEADS + h] + er[n * HEADS + h];
    x = x > 0.f ? x : NEG_SLOPE * x;

    float m = x;
    #pragma unroll
    for (int msk = 8; msk >= 1; msk >>= 1) m = fmaxf(m, __shfl_xor(m, msk));
    float ex = __expf(x - m);
    float s = ex;
    #pragma unroll
    for (int msk = 8; msk >= 1; msk >>= 1) s += __shfl_xor(s, msk);

    s_alpha[w][h][k] = ex / s;
    if (l < DEG) s_src[w][l] = src_k;
    __syncthreads();

    const int l41 = l < 41 ? l : 40;
    const int c0 = 4 * l41;
    const int h0 = (c0 + 0) / 41, h1 = (c0 + 1) / 41;
    const int h2 = (c0 + 2) / 41, h3 = (c0 + 3) / 41;

    float4 acc = make_float4(0.f, 0.f, 0.f, 0.f);
    #pragma unroll
    for (int k2 = 0; k2 < DEG; ++k2) {
        const int sk = s_src[w][k2];
        ushort4 f = *reinterpret_cast<const ushort4*>(&featb[(size_t)sk * 164 + c0]);
        acc.x += s_alpha[w][h0][k2] * bf2f(f.x);
        acc.y += s_alpha[w][h1][k2] * bf2f(f.y);
        acc.z += s_alpha[w][h2][k2] * bf2f(f.z);
        acc.w += s_alpha[w][h3][k2] * bf2f(f.w);
    }
    if (l < 41) *reinterpret_cast<float4*>(&s_agg[w][c0]) = acc;
    __syncthreads();
    if (l < 41)
        out[(size_t)n * 41 + l] =
            0.25f * (s_agg[w][l] + s_agg[w][l + 41] + s_agg[w][l + 82] + s_agg[w][l + 123]);
}

extern "C" void kernel_launch(void* const* d_in, const int* in_sizes, int n_in,
                              void* d_out, int out_size, void* d_ws, size_t ws_size,
                              hipStream_t stream)
{
    const int*   col_ind = (const int*)  d_in[1];
    const float* inputs  = (const float*)d_in[2];
    const float* W0      = (const float*)d_in[3];
    const float* al0     = (const float*)d_in[4];
    const float* ar0     = (const float*)d_in[5];
    const float* W1      = (const float*)d_in[6];
    const float* al1     = (const float*)d_in[7];
    const float* ar1     = (const float*)d_in[8];
    const float* W2      = (const float*)d_in[9];
    const float* al2     = (const float*)d_in[10];
    const float* ar2     = (const float*)d_in[11];
    float* out = (float*)d_out;

    char* ws = (char*)d_ws;
    const size_t seg = (size_t)NPAD * 256 * sizeof(ushort_t);   // 51.25 MB
    ushort_t* h_hi  = (ushort_t*)(ws);
    ushort_t* h_lo  = (ushort_t*)(ws + seg);
    ushort_t* featb = (ushort_t*)(ws + 2 * seg);   // linear [NN][256] (L0/1) or [NN][164] (L2)
    uint32_t* salph = (uint32_t*)(ws + 3 * seg);   // 25.6 MB
    float*    el    = (float*)(ws + 3 * seg + (size_t)NN * 64 * 4);
    float*    er    = el + (size_t)NN * HEADS;
    ushort_t* wt    = (ushort_t*)(er + (size_t)NN * HEADS);
    ushort_t* wt0h = wt;              ushort_t* wt0l = wt + 65536;
    ushort_t* wt1h = wt + 2 * 65536;  ushort_t* wt1l = wt + 3 * 65536;
    ushort_t* wt2h = wt + 4 * 65536;  ushort_t* wt2l = wt + 5 * 65536;

    dim3 blk(256);
    dim3 gg(2, (NN + 127) / 128);
    const int nodeGrid = NN / 4;         // 25000 (alpha_prep, agg_out)
    const int sliceGrid = (NN / 32) * 8; // 25000 (agg_sliced)

    prep_wt<<<256, blk, 0, stream>>>(W0, wt0h, wt0l, 256);
    prep_wt<<<256, blk, 0, stream>>>(W1, wt1h, wt1l, 256);
    prep_wt<<<256, blk, 0, stream>>>(W2, wt2h, wt2l, 164);

    // Layer 0
    gemm_mfma<0, true><<<gg, blk, 0, stream>>>(
        inputs, nullptr, nullptr, wt0h, wt0l, al0, ar0, featb, 256, 256, el, er);
    alpha_prep<<<nodeGrid, blk, 0, stream>>>(el, er, col_ind, salph);
    agg_sliced<<<sliceGrid, blk, 0, stream>>>(featb, salph, h_hi, h_lo);

    // Layer 1
    gemm_mfma<1, true><<<gg, blk, 0, stream>>>(
        nullptr, h_hi, h_lo, wt1h, wt1l, al1, ar1, featb, 256, 256, el, er);
    alpha_prep<<<nodeGrid, blk, 0, stream>>>(el, er, col_ind, salph);
    agg_sliced<<<sliceGrid, blk, 0, stream>>>(featb, salph, h_hi, h_lo);

    // Layer 2: linear epilogue (164 cols), classic scores + agg_out
    gemm_mfma<1, false><<<gg, blk, 0, stream>>>(
        nullptr, h_hi, h_lo, wt2h, wt2l, nullptr, nullptr, featb, 164, 164, nullptr, nullptr);
    scores2_bf<<<NN, blk, 0, stream>>>(featb, al2, ar2, el, er);
    agg_out_bf<<<nodeGrid, blk, 0, stream>>>(featb, el, er, col_ind, out);
}

// Round 11
// 653.655 us; speedup vs baseline: 1.2849x; 1.2849x over previous
//
#include <hip/hip_runtime.h>

#define NN 100000
#define DEG 16
#define HEADS 4
#define NEG_SLOPE 0.2f
#define NPAD 100096   // 782 * 128

typedef unsigned short ushort_t;
typedef __attribute__((ext_vector_type(8))) short bf16x8;
typedef __attribute__((ext_vector_type(4))) float f32x4;

__device__ __forceinline__ ushort_t f2bf_rn(float f) {
    uint32_t u = __float_as_uint(f);
    uint32_t r = (u + 0x7fffu + ((u >> 16) & 1u)) >> 16;
    return (ushort_t)r;
}
__device__ __forceinline__ float bf2f(ushort_t u) {
    return __uint_as_float(((uint32_t)u) << 16);
}

// async 16B global->LDS DMA: LDS dest = wave-uniform base + lane*16
__device__ __forceinline__ void gld16(const void* g, void* l) {
    __builtin_amdgcn_global_load_lds(
        (const __attribute__((address_space(1))) unsigned int*)g,
        (__attribute__((address_space(3))) unsigned int*)l, 16, 0, 0);
}

// ---- prep: W[k][col] -> per-K32-step fragment-linear hi/lo bf16 panels -----
// 16B chunks: [p][k32][wn][nf][ln], elem j:
//   col = p*128 + wn*64 + nf*16 + (ln&15) ;  k = k32*32 + (ln>>4)*8 + j
__global__ __launch_bounds__(256) void prep_wt(
    const float* __restrict__ W, ushort_t* __restrict__ Wh,
    ushort_t* __restrict__ Wl, int ncr)
{
    int idx = blockIdx.x * 256 + threadIdx.x;   // 65536 elements
    int j     = idx & 7;
    int chunk = idx >> 3;
    int ln  = chunk & 63;
    int nf  = (chunk >> 6) & 3;
    int wn  = (chunk >> 8) & 1;
    int k32 = (chunk >> 9) & 7;
    int p   = (chunk >> 12) & 1;
    int col = p * 128 + wn * 64 + nf * 16 + (ln & 15);
    int k   = k32 * 32 + (ln >> 4) * 8 + j;
    float v = (col < ncr) ? W[k * ncr + col] : 0.f;
    uint32_t b  = __float_as_uint(v);
    uint32_t hb = b & 0xffff0000u;
    float r = v - __uint_as_float(hb);
    Wh[idx] = (ushort_t)(hb >> 16);
    Wl[idx] = (ushort_t)(__float_as_uint(r) >> 16);
}

// ---- split-bf16 MFMA GEMM, 2-phase double-buffered pipeline ----------------
// BK=32, 8 steps. Per buffer: Ahi 8K | Alo 8K | Bhi 8K | Blo 8K = 32KB, x2.
// AMODE 0: fp32 A (layer 0, T14 reg-split).  AMODE 1: presplit via gload_lds.
template <int AMODE, bool DO_SCORES>
__global__ __launch_bounds__(256) void gemm_mfma(
    const float* __restrict__ A32,
    const ushort_t* __restrict__ Ahi, const ushort_t* __restrict__ Alo,
    const ushort_t* __restrict__ Bth, const ushort_t* __restrict__ Btl,
    const float* __restrict__ al, const float* __restrict__ ar,
    ushort_t* __restrict__ Cb, int ldc, int ncr,
    float* __restrict__ el, float* __restrict__ er)
{
    __shared__ uint4 smem[4096];   // 64 KB

    const int tid  = threadIdx.x;
    const int wv   = tid >> 6;
    const int ln   = tid & 63;
    const int wm   = wv >> 1;
    const int wn   = wv & 1;
    const int cl   = ln & 15;
    const int kq   = ln >> 4;
    const int row0 = blockIdx.y * 128;
    const int col0 = blockIdx.x * 128;

    const ushort_t* bH = Bth + (size_t)blockIdx.x * 32768;
    const ushort_t* bL = Btl + (size_t)blockIdx.x * 32768;

    f32x4 acc[4][4] = {};
    float4 ra0[2], ra1[2];   // AMODE 0 staging regs

    auto stageB = [&](int b, int step) {
        const ushort_t* rh = bH + step * 4096;
        const ushort_t* rl = bL + step * 4096;
        char* dh = (char*)smem + b * 32768 + 16384;
        char* dl = dh + 8192;
        #pragma unroll
        for (int q = 0; q < 2; ++q) {
            int i = wv * 2 + q;
            gld16(rh + (size_t)(i * 64 + ln) * 8, dh + i * 1024);
            gld16(rl + (size_t)(i * 64 + ln) * 8, dl + i * 1024);
        }
    };
    auto stageA1 = [&](int b, int step) {
        const int rsub = ln >> 2;                    // 0..15 within 16-row block
        const int c    = (ln & 3) ^ ((ln >> 3) & 3); // swizzled source chunk
        char* dh = (char*)smem + b * 32768;
        char* dl = dh + 8192;
        #pragma unroll
        for (int q = 0; q < 2; ++q) {
            int rb = wv * 2 + q;                     // 16-row block 0..7
            size_t g = (size_t)(row0 + rb * 16 + rsub) * 256 + step * 32 + c * 8;
            gld16(Ahi + g, dh + rb * 1024);
            gld16(Alo + g, dl + rb * 1024);
        }
    };
    auto loadA0 = [&](int step) {
        #pragma unroll
        for (int u = 0; u < 2; ++u) {
            int qq = u * 256 + tid;                  // chunk id 0..511
            int row = qq >> 2, s = qq & 3;
            int c = s ^ ((row >> 1) & 3);
            int gr = row0 + row;
            float4 v0 = make_float4(0.f, 0.f, 0.f, 0.f), v1 = v0;
            if (gr < NN) {
                const float* g = A32 + (size_t)gr * 256 + step * 32 + c * 8;
                v0 = *reinterpret_cast<const float4*>(g);
                v1 = *reinterpret_cast<const float4*>(g + 4);
            }
            ra0[u] = v0; ra1[u] = v1;
        }
    };
    auto writeA0 = [&](int b) {
        uint4* dh = smem + b * 2048;
        uint4* dl = dh + 512;
        #pragma unroll
        for (int u = 0; u < 2; ++u) {
            int qq = u * 256 + tid;
            int row = qq >> 2, s = qq & 3;
            float4 v0 = ra0[u], v1 = ra1[u];
            uint32_t b0 = __float_as_uint(v0.x), b1 = __float_as_uint(v0.y);
            uint32_t b2 = __float_as_uint(v0.z), b3 = __float_as_uint(v0.w);
            uint32_t b4 = __float_as_uint(v1.x), b5 = __float_as_uint(v1.y);
            uint32_t b6 = __float_as_uint(v1.z), b7 = __float_as_uint(v1.w);
            uint4 vh;
            vh.x = (b1 & 0xffff0000u) | (b0 >> 16);
            vh.y = (b3 & 0xffff0000u) | (b2 >> 16);
            vh.z = (b5 & 0xffff0000u) | (b4 >> 16);
            vh.w = (b7 & 0xffff0000u) | (b6 >> 16);
            float r0 = v0.x - __uint_as_float(b0 & 0xffff0000u);
            float r1 = v0.y - __uint_as_float(b1 & 0xffff0000u);
            float r2 = v0.z - __uint_as_float(b2 & 0xffff0000u);
            float r3 = v0.w - __uint_as_float(b3 & 0xffff0000u);
            float r4 = v1.x - __uint_as_float(b4 & 0xffff0000u);
            float r5 = v1.y - __uint_as_float(b5 & 0xffff0000u);
            float r6 = v1.z - __uint_as_float(b6 & 0xffff0000u);
            float r7 = v1.w - __uint_as_float(b7 & 0xffff0000u);
            uint4 vl;
            vl.x = (__float_as_uint(r1) & 0xffff0000u) | (__float_as_uint(r0) >> 16);
            vl.y = (__float_as_uint(r3) & 0xffff0000u) | (__float_as_uint(r2) >> 16);
            vl.z = (__float_as_uint(r5) & 0xffff0000u) | (__float_as_uint(r4) >> 16);
            vl.w = (__float_as_uint(r7) & 0xffff0000u) | (__float_as_uint(r6) >> 16);
            dh[row * 4 + s] = vh;
            dl[row * 4 + s] = vl;
        }
    };
    auto compute = [&](int b) {
        const bf16x8* aH  = (const bf16x8*)((char*)smem + b * 32768);
        const bf16x8* aL  = (const bf16x8*)((char*)smem + b * 32768 + 8192);
        const bf16x8* pbH = (const bf16x8*)((char*)smem + b * 32768 + 16384);
        const bf16x8* pbL = (const bf16x8*)((char*)smem + b * 32768 + 24576);
        bf16x8 ah[4], ax[4];
        const int slot = kq ^ ((cl >> 1) & 3);
        #pragma unroll
        for (int mf = 0; mf < 4; ++mf) {
            int row = wm * 64 + mf * 16 + cl;
            int idx = row * 4 + slot;
            ah[mf] = aH[idx];
            ax[mf] = aL[idx];
        }
        #pragma unroll
        for (int nf = 0; nf < 4; ++nf) {
            int bidx = (wn * 4 + nf) * 64 + ln;
            bf16x8 bh = pbH[bidx];
            bf16x8 bl = pbL[bidx];
            #pragma unroll
            for (int mf = 0; mf < 4; ++mf) {
                acc[mf][nf] = __builtin_amdgcn_mfma_f32_16x16x32_bf16(ah[mf], bh, acc[mf][nf], 0, 0, 0);
                acc[mf][nf] = __builtin_amdgcn_mfma_f32_16x16x32_bf16(ah[mf], bl, acc[mf][nf], 0, 0, 0);
                acc[mf][nf] = __builtin_amdgcn_mfma_f32_16x16x32_bf16(ax[mf], bh, acc[mf][nf], 0, 0, 0);
            }
        }
    };

    // ---- prologue: stage step 0 into buf 0 -------------------------------
    stageB(0, 0);
    if (AMODE == 1) {
        stageA1(0, 0);
    } else {
        loadA0(0);
        writeA0(0);
    }
    __syncthreads();

    // ---- 2-phase pipeline: issue stage(t+1) before compute(t) ------------
    #pragma unroll 2
    for (int step = 0; step < 8; ++step) {
        const int b = step & 1;
        if (step < 7) {
            stageB(b ^ 1, step + 1);
            if (AMODE == 1) stageA1(b ^ 1, step + 1);
            else            loadA0(step + 1);      // raw loads only
        }
        compute(b);
        if (AMODE == 0 && step < 7) writeA0(b ^ 1); // split+write after compute
        __syncthreads();
    }

    // ---- epilogue: linear bf16 C store (+ fused scores) ------------------
    #pragma unroll
    for (int mf = 0; mf < 4; ++mf) {
        int gr0 = row0 + wm * 64 + mf * 16 + kq * 4;
        #pragma unroll
        for (int r = 0; r < 4; ++r) {
            int gr = gr0 + r;
            if (gr < NN) {
                #pragma unroll
                for (int nf = 0; nf < 4; ++nf) {
                    int gc = col0 + wn * 64 + nf * 16 + cl;
                    if (gc < ncr)
                        Cb[(size_t)gr * ldc + gc] = f2bf_rn(acc[mf][nf][r]);
                }
            }
        }
    }

    if (DO_SCORES) {
        const int head = blockIdx.x * 2 + wn;
        float alv[4], arv[4];
        #pragma unroll
        for (int nf = 0; nf < 4; ++nf) {
            int d = nf * 16 + cl;
            alv[nf] = al[head * 64 + d];
            arv[nf] = ar[head * 64 + d];
        }
        #pragma unroll
        for (int mf = 0; mf < 4; ++mf) {
            #pragma unroll
            for (int r = 0; r < 4; ++r) {
                float pl = 0.f, pr = 0.f;
                #pragma unroll
                for (int nf = 0; nf < 4; ++nf) {
                    pl += acc[mf][nf][r] * alv[nf];
                    pr += acc[mf][nf][r] * arv[nf];
                }
                #pragma unroll
                for (int msk = 1; msk <= 8; msk <<= 1) {
                    pl += __shfl_xor(pl, msk);
                    pr += __shfl_xor(pr, msk);
                }
                if (cl == 0) {
                    int gr = row0 + wm * 64 + mf * 16 + kq * 4 + r;
                    if (gr < NN) {
                        el[gr * HEADS + head] = pl;
                        er[gr * HEADS + head] = pr;
                    }
                }
            }
        }
    }
}

// ---- layer-2 scores from bf16 feat (D=41, HD=164) --------------------------
__global__ __launch_bounds__(256) void scores2_bf(
    const ushort_t* __restrict__ featb, const float* __restrict__ al,
    const float* __restrict__ ar, float* __restrict__ el, float* __restrict__ er)
{
    const int n = blockIdx.x;
    const int t = threadIdx.x;
    const int h = t >> 6;
    const int j = t & 63;
    float v = 0.f, u = 0.f;
    if (j < 41) {
        float f = bf2f(featb[(size_t)n * 164 + h * 41 + j]);
        v = f * al[h * 41 + j];
        u = f * ar[h * 41 + j];
    }
    #pragma unroll
    for (int off = 32; off > 0; off >>= 1) {
        v += __shfl_down(v, off);
        u += __shfl_down(u, off);
    }
    if (j == 0) {
        el[n * HEADS + h] = v;
        er[n * HEADS + h] = u;
    }
}

// ---- aggregation (HD=256): wave per node; writes h as hi/lo split ----------
__global__ __launch_bounds__(256) void agg_full_bf(
    const ushort_t* __restrict__ featb, const float* __restrict__ el,
    const float* __restrict__ er, const int* __restrict__ col,
    ushort_t* __restrict__ Hhi, ushort_t* __restrict__ Hlo)
{
    __shared__ int   s_src[4][DEG];
    __shared__ float s_alpha[4][HEADS][DEG];

    const int t = threadIdx.x;
    const int w = t >> 6;
    const int l = t & 63;
    const int n = blockIdx.x * 4 + w;
    const int h = l >> 4;
    const int k = l & 15;

    const int src_k = col[n * DEG + k];
    float x = el[src_k * HEADS + h] + er[n * HEADS + h];
    x = x > 0.f ? x : NEG_SLOPE * x;

    float m = x;
    #pragma unroll
    for (int msk = 8; msk >= 1; msk >>= 1) m = fmaxf(m, __shfl_xor(m, msk));
    float ex = __expf(x - m);
    float s = ex;
    #pragma unroll
    for (int msk = 8; msk >= 1; msk >>= 1) s += __shfl_xor(s, msk);

    s_alpha[w][h][k] = ex / s;
    if (l < DEG) s_src[w][l] = src_k;
    __syncthreads();

    float4 acc = make_float4(0.f, 0.f, 0.f, 0.f);
    #pragma unroll
    for (int k2 = 0; k2 < DEG; ++k2) {
        const int   sk = s_src[w][k2];
        const float a  = s_alpha[w][h][k2];
        ushort4 f = *reinterpret_cast<const ushort4*>(&featb[(size_t)sk * 256 + l * 4]);
        acc.x += a * bf2f(f.x);
        acc.y += a * bf2f(f.y);
        acc.z += a * bf2f(f.z);
        acc.w += a * bf2f(f.w);
    }
    uint32_t bx = __float_as_uint(acc.x), by = __float_as_uint(acc.y);
    uint32_t bz = __float_as_uint(acc.z), bw = __float_as_uint(acc.w);
    ushort4 hv;
    hv.x = (ushort_t)(bx >> 16); hv.y = (ushort_t)(by >> 16);
    hv.z = (ushort_t)(bz >> 16); hv.w = (ushort_t)(bw >> 16);
    float rx = acc.x - __uint_as_float(bx & 0xffff0000u);
    float ry = acc.y - __uint_as_float(by & 0xffff0000u);
    float rz = acc.z - __uint_as_float(bz & 0xffff0000u);
    float rw = acc.w - __uint_as_float(bw & 0xffff0000u);
    ushort4 lv;
    lv.x = (ushort_t)(__float_as_uint(rx) >> 16);
    lv.y = (ushort_t)(__float_as_uint(ry) >> 16);
    lv.z = (ushort_t)(__float_as_uint(rz) >> 16);
    lv.w = (ushort_t)(__float_as_uint(rw) >> 16);
    *reinterpret_cast<ushort4*>(&Hhi[(size_t)n * 256 + l * 4]) = hv;
    *reinterpret_cast<ushort4*>(&Hlo[(size_t)n * 256 + l * 4]) = lv;
}

// ---- output-layer aggregation (HD=164, mean over heads) --------------------
__global__ __launch_bounds__(256) void agg_out_bf(
    const ushort_t* __restrict__ featb, const float* __restrict__ el,
    const float* __restrict__ er, const int* __restrict__ col,
    float* __restrict__ out)   // out: [N, 41]
{
    __shared__ int   s_src[4][DEG];
    __shared__ float s_alpha[4][HEADS][DEG];
    __shared__ float s_agg[4][164];

    const int t = threadIdx.x;
    const int w = t >> 6;
    const int l = t & 63;
    const int n = blockIdx.x * 4 + w;
    const int h = l >> 4;
    const int k = l & 15;

    const int src_k = col[n * DEG + k];
    float x = el[src_k * HEADS + h] + er[n * HEADS + h];
    x = x > 0.f ? x : NEG_SLOPE * x;

    float m = x;
    #pragma unroll
    for (int msk = 8; msk >= 1; msk >>= 1) m = fmaxf(m, __shfl_xor(m, msk));
    float ex = __expf(x - m);
    float s = ex;
    #pragma unroll
    for (int msk = 8; msk >= 1; msk >>= 1) s += __shfl_xor(s, msk);

    s_alpha[w][h][k] = ex / s;
    if (l < DEG) s_src[w][l] = src_k;
    __syncthreads();

    const int l41 = l < 41 ? l : 40;
    const int c0 = 4 * l41;
    const int h0 = (c0 + 0) / 41, h1 = (c0 + 1) / 41;
    const int h2 = (c0 + 2) / 41, h3 = (c0 + 3) / 41;

    float4 acc = make_float4(0.f, 0.f, 0.f, 0.f);
    #pragma unroll
    for (int k2 = 0; k2 < DEG; ++k2) {
        const int sk = s_src[w][k2];
        ushort4 f = *reinterpret_cast<const ushort4*>(&featb[(size_t)sk * 164 + c0]);
        acc.x += s_alpha[w][h0][k2] * bf2f(f.x);
        acc.y += s_alpha[w][h1][k2] * bf2f(f.y);
        acc.z += s_alpha[w][h2][k2] * bf2f(f.z);
        acc.w += s_alpha[w][h3][k2] * bf2f(f.w);
    }
    if (l < 41) *reinterpret_cast<float4*>(&s_agg[w][c0]) = acc;
    __syncthreads();
    if (l < 41)
        out[(size_t)n * 41 + l] =
            0.25f * (s_agg[w][l] + s_agg[w][l + 41] + s_agg[w][l + 82] + s_agg[w][l + 123]);
}

extern "C" void kernel_launch(void* const* d_in, const int* in_sizes, int n_in,
                              void* d_out, int out_size, void* d_ws, size_t ws_size,
                              hipStream_t stream)
{
    const int*   col_ind = (const int*)  d_in[1];
    const float* inputs  = (const float*)d_in[2];
    const float* W0      = (const float*)d_in[3];
    const float* al0     = (const float*)d_in[4];
    const float* ar0     = (const float*)d_in[5];
    const float* W1      = (const float*)d_in[6];
    const float* al1     = (const float*)d_in[7];
    const float* ar1     = (const float*)d_in[8];
    const float* W2      = (const float*)d_in[9];
    const float* al2     = (const float*)d_in[10];
    const float* ar2     = (const float*)d_in[11];
    float* out = (float*)d_out;

    char* ws = (char*)d_ws;
    const size_t seg = (size_t)NPAD * 256 * sizeof(ushort_t);   // 51.25 MB
    ushort_t* h_hi  = (ushort_t*)(ws);
    ushort_t* h_lo  = (ushort_t*)(ws + seg);
    ushort_t* featb = (ushort_t*)(ws + 2 * seg);
    float*    el    = (float*)(ws + 3 * seg);
    float*    er    = el + (size_t)NN * HEADS;
    ushort_t* wt    = (ushort_t*)(er + (size_t)NN * HEADS);
    ushort_t* wt0h = wt;              ushort_t* wt0l = wt + 65536;
    ushort_t* wt1h = wt + 2 * 65536;  ushort_t* wt1l = wt + 3 * 65536;
    ushort_t* wt2h = wt + 4 * 65536;  ushort_t* wt2l = wt + 5 * 65536;

    dim3 blk(256);
    dim3 gg(2, (NN + 127) / 128);
    const int waveGrid = NN / 4;

    prep_wt<<<256, blk, 0, stream>>>(W0, wt0h, wt0l, 256);
    prep_wt<<<256, blk, 0, stream>>>(W1, wt1h, wt1l, 256);
    prep_wt<<<256, blk, 0, stream>>>(W2, wt2h, wt2l, 164);

    // Layer 0: fp32 A path, fused scores
    gemm_mfma<0, true><<<gg, blk, 0, stream>>>(
        inputs, nullptr, nullptr, wt0h, wt0l, al0, ar0, featb, 256, 256, el, er);
    agg_full_bf<<<waveGrid, blk, 0, stream>>>(featb, el, er, col_ind, h_hi, h_lo);

    // Layer 1: presplit A path, fused scores
    gemm_mfma<1, true><<<gg, blk, 0, stream>>>(
        nullptr, h_hi, h_lo, wt1h, wt1l, al1, ar1, featb, 256, 256, el, er);
    agg_full_bf<<<waveGrid, blk, 0, stream>>>(featb, el, er, col_ind, h_hi, h_lo);

    // Layer 2: presplit A, no fused scores
    gemm_mfma<1, false><<<gg, blk, 0, stream>>>(
        nullptr, h_hi, h_lo, wt2h, wt2l, nullptr, nullptr, featb, 164, 164, nullptr, nullptr);
    scores2_bf<<<NN, blk, 0, stream>>>(featb, al2, ar2, el, er);
    agg_out_bf<<<waveGrid, blk, 0, stream>>>(featb, el, er, col_ind, out);
}

// Round 14
// 637.935 us; speedup vs baseline: 1.3165x; 1.0246x over previous
//
#include <hip/hip_runtime.h>

#define NN 100000
#define DEG 16
#define HEADS 4
#define NEG_SLOPE 0.2f
#define NPAD 100096   // 782 * 128

typedef unsigned short ushort_t;
typedef __attribute__((ext_vector_type(8))) short bf16x8;
typedef __attribute__((ext_vector_type(4))) float f32x4;

__device__ __forceinline__ ushort_t f2bf_rn(float f) {
    uint32_t u = __float_as_uint(f);
    uint32_t r = (u + 0x7fffu + ((u >> 16) & 1u)) >> 16;
    return (ushort_t)r;
}
__device__ __forceinline__ float bf2f(ushort_t u) {
    return __uint_as_float(((uint32_t)u) << 16);
}

// async 16B global->LDS DMA: LDS dest = wave-uniform base + lane*16
__device__ __forceinline__ void gld16(const void* g, void* l) {
    __builtin_amdgcn_global_load_lds(
        (const __attribute__((address_space(1))) unsigned int*)g,
        (__attribute__((address_space(3))) unsigned int*)l, 16, 0, 0);
}

// ---- prep: W[k][col] -> per-K32-step fragment-linear hi/lo bf16 panels -----
// 16B chunks: [p][k32][wn][nf][ln], elem j:
//   col = p*128 + wn*64 + nf*16 + (ln&15) ;  k = k32*32 + (ln>>4)*8 + j
__global__ __launch_bounds__(256) void prep_wt(
    const float* __restrict__ W, ushort_t* __restrict__ Wh,
    ushort_t* __restrict__ Wl, int ncr)
{
    int idx = blockIdx.x * 256 + threadIdx.x;   // 65536 elements
    int j     = idx & 7;
    int chunk = idx >> 3;
    int ln  = chunk & 63;
    int nf  = (chunk >> 6) & 3;
    int wn  = (chunk >> 8) & 1;
    int k32 = (chunk >> 9) & 7;
    int p   = (chunk >> 12) & 1;
    int col = p * 128 + wn * 64 + nf * 16 + (ln & 15);
    int k   = k32 * 32 + (ln >> 4) * 8 + j;
    float v = (col < ncr) ? W[k * ncr + col] : 0.f;
    uint32_t b  = __float_as_uint(v);
    uint32_t hb = b & 0xffff0000u;
    float r = v - __uint_as_float(hb);
    Wh[idx] = (ushort_t)(hb >> 16);
    Wl[idx] = (ushort_t)(__float_as_uint(r) >> 16);
}

// ---- split-bf16 MFMA GEMM, counted-vmcnt double-buffered pipeline ----------
// BK=32, 8 steps. Per buffer: Ahi 8K | Alo 8K | Bhi 8K | Blo 8K = 32KB, x2.
// AMODE 0: fp32 A (layer 0, reg-split, syncthreads schedule).
// AMODE 1: presplit bf16 via gload_lds, 2-step-ahead stage + vmcnt(8).
template <int AMODE, bool DO_SCORES>
__global__ __launch_bounds__(256) void gemm_mfma(
    const float* __restrict__ A32,
    const ushort_t* __restrict__ Ahi, const ushort_t* __restrict__ Alo,
    const ushort_t* __restrict__ Bth, const ushort_t* __restrict__ Btl,
    const float* __restrict__ al, const float* __restrict__ ar,
    ushort_t* __restrict__ Cb, int ldc, int ncr,
    float* __restrict__ el, float* __restrict__ er)
{
    __shared__ uint4 smem[4096];   // 64 KB

    const int tid  = threadIdx.x;
    const int wv   = tid >> 6;
    const int ln   = tid & 63;
    const int wm   = wv >> 1;
    const int wn   = wv & 1;
    const int cl   = ln & 15;
    const int kq   = ln >> 4;
    const int row0 = blockIdx.y * 128;
    const int col0 = blockIdx.x * 128;

    const ushort_t* bH = Bth + (size_t)blockIdx.x * 32768;
    const ushort_t* bL = Btl + (size_t)blockIdx.x * 32768;

    f32x4 acc[4][4] = {};
    float4 ra0[2], ra1[2];   // AMODE 0 staging regs

    auto stageB = [&](int b, int step) {
        const ushort_t* rh = bH + step * 4096;
        const ushort_t* rl = bL + step * 4096;
        char* dh = (char*)smem + b * 32768 + 16384;
        char* dl = dh + 8192;
        #pragma unroll
        for (int q = 0; q < 2; ++q) {
            int i = wv * 2 + q;
            gld16(rh + (size_t)(i * 64 + ln) * 8, dh + i * 1024);
            gld16(rl + (size_t)(i * 64 + ln) * 8, dl + i * 1024);
        }
    };
    auto stageA1 = [&](int b, int step) {
        const int rsub = ln >> 2;                    // 0..15 within 16-row block
        const int c    = (ln & 3) ^ ((ln >> 3) & 3); // swizzled source chunk
        char* dh = (char*)smem + b * 32768;
        char* dl = dh + 8192;
        #pragma unroll
        for (int q = 0; q < 2; ++q) {
            int rb = wv * 2 + q;                     // 16-row block 0..7
            size_t g = (size_t)(row0 + rb * 16 + rsub) * 256 + step * 32 + c * 8;
            gld16(Ahi + g, dh + rb * 1024);
            gld16(Alo + g, dl + rb * 1024);
        }
    };
    auto loadA0 = [&](int step) {
        #pragma unroll
        for (int u = 0; u < 2; ++u) {
            int qq = u * 256 + tid;                  // chunk id 0..511
            int row = qq >> 2, s = qq & 3;
            int c = s ^ ((row >> 1) & 3);
            int gr = row0 + row;
            float4 v0 = make_float4(0.f, 0.f, 0.f, 0.f), v1 = v0;
            if (gr < NN) {
                const float* g = A32 + (size_t)gr * 256 + step * 32 + c * 8;
                v0 = *reinterpret_cast<const float4*>(g);
                v1 = *reinterpret_cast<const float4*>(g + 4);
            }
            ra0[u] = v0; ra1[u] = v1;
        }
    };
    auto writeA0 = [&](int b) {
        uint4* dh = smem + b * 2048;
        uint4* dl = dh + 512;
        #pragma unroll
        for (int u = 0; u < 2; ++u) {
            int qq = u * 256 + tid;
            int row = qq >> 2, s = qq & 3;
            float4 v0 = ra0[u], v1 = ra1[u];
            uint32_t b0 = __float_as_uint(v0.x), b1 = __float_as_uint(v0.y);
            uint32_t b2 = __float_as_uint(v0.z), b3 = __float_as_uint(v0.w);
            uint32_t b4 = __float_as_uint(v1.x), b5 = __float_as_uint(v1.y);
            uint32_t b6 = __float_as_uint(v1.z), b7 = __float_as_uint(v1.w);
            uint4 vh;
            vh.x = (b1 & 0xffff0000u) | (b0 >> 16);
            vh.y = (b3 & 0xffff0000u) | (b2 >> 16);
            vh.z = (b5 & 0xffff0000u) | (b4 >> 16);
            vh.w = (b7 & 0xffff0000u) | (b6 >> 16);
            float r0 = v0.x - __uint_as_float(b0 & 0xffff0000u);
            float r1 = v0.y - __uint_as_float(b1 & 0xffff0000u);
            float r2 = v0.z - __uint_as_float(b2 & 0xffff0000u);
            float r3 = v0.w - __uint_as_float(b3 & 0xffff0000u);
            float r4 = v1.x - __uint_as_float(b4 & 0xffff0000u);
            float r5 = v1.y - __uint_as_float(b5 & 0xffff0000u);
            float r6 = v1.z - __uint_as_float(b6 & 0xffff0000u);
            float r7 = v1.w - __uint_as_float(b7 & 0xffff0000u);
            uint4 vl;
            vl.x = (__float_as_uint(r1) & 0xffff0000u) | (__float_as_uint(r0) >> 16);
            vl.y = (__float_as_uint(r3) & 0xffff0000u) | (__float_as_uint(r2) >> 16);
            vl.z = (__float_as_uint(r5) & 0xffff0000u) | (__float_as_uint(r4) >> 16);
            vl.w = (__float_as_uint(r7) & 0xffff0000u) | (__float_as_uint(r6) >> 16);
            dh[row * 4 + s] = vh;
            dl[row * 4 + s] = vl;
        }
    };
    auto compute = [&](int b) {
        const bf16x8* aH  = (const bf16x8*)((char*)smem + b * 32768);
        const bf16x8* aL  = (const bf16x8*)((char*)smem + b * 32768 + 8192);
        const bf16x8* pbH = (const bf16x8*)((char*)smem + b * 32768 + 16384);
        const bf16x8* pbL = (const bf16x8*)((char*)smem + b * 32768 + 24576);
        bf16x8 ah[4], ax[4];
        const int slot = kq ^ ((cl >> 1) & 3);
        #pragma unroll
        for (int mf = 0; mf < 4; ++mf) {
            int row = wm * 64 + mf * 16 + cl;
            int idx = row * 4 + slot;
            ah[mf] = aH[idx];
            ax[mf] = aL[idx];
        }
        #pragma unroll
        for (int nf = 0; nf < 4; ++nf) {
            int bidx = (wn * 4 + nf) * 64 + ln;
            bf16x8 bh = pbH[bidx];
            bf16x8 bl = pbL[bidx];
            #pragma unroll
            for (int mf = 0; mf < 4; ++mf) {
                acc[mf][nf] = __builtin_amdgcn_mfma_f32_16x16x32_bf16(ah[mf], bh, acc[mf][nf], 0, 0, 0);
                acc[mf][nf] = __builtin_amdgcn_mfma_f32_16x16x32_bf16(ah[mf], bl, acc[mf][nf], 0, 0, 0);
                acc[mf][nf] = __builtin_amdgcn_mfma_f32_16x16x32_bf16(ax[mf], bh, acc[mf][nf], 0, 0, 0);
            }
        }
    };

    if (AMODE == 0) {
        // ---- layer-0 schedule (R11): 1-step-ahead + syncthreads ----------
        stageB(0, 0);
        loadA0(0);
        writeA0(0);
        __syncthreads();
        #pragma unroll 2
        for (int step = 0; step < 8; ++step) {
            const int b = step & 1;
            if (step < 7) {
                stageB(b ^ 1, step + 1);
                loadA0(step + 1);
            }
            compute(b);
            if (step < 7) writeA0(b ^ 1);
            __syncthreads();
        }
    } else {
        // ---- counted-vmcnt schedule: 2 steps in flight -------------------
        stageB(0, 0); stageA1(0, 0);      // 8 loads (buf 0)
        stageB(1, 1); stageA1(1, 1);      // 8 loads (buf 1)
        #pragma unroll
        for (int step = 0; step < 8; ++step) {
            const int b = step & 1;
            // wait for buf b's loads; keep the other buffer's 8 in flight
            if (step < 7)
                asm volatile("s_waitcnt vmcnt(8)\n\ts_barrier" ::: "memory");
            else
                asm volatile("s_waitcnt vmcnt(0)\n\ts_barrier" ::: "memory");
            compute(b);
            asm volatile("s_barrier" ::: "memory");   // all waves done reading buf b
            if (step < 6) { stageB(b, step + 2); stageA1(b, step + 2); }
        }
    }

    // ---- epilogue: linear bf16 C store (+ fused scores) ------------------
    #pragma unroll
    for (int mf = 0; mf < 4; ++mf) {
        int gr0 = row0 + wm * 64 + mf * 16 + kq * 4;
        #pragma unroll
        for (int r = 0; r < 4; ++r) {
            int gr = gr0 + r;
            if (gr < NN) {
                #pragma unroll
                for (int nf = 0; nf < 4; ++nf) {
                    int gc = col0 + wn * 64 + nf * 16 + cl;
                    if (gc < ncr)
                        Cb[(size_t)gr * ldc + gc] = f2bf_rn(acc[mf][nf][r]);
                }
            }
        }
    }

    if (DO_SCORES) {
        const int head = blockIdx.x * 2 + wn;
        float alv[4], arv[4];
        #pragma unroll
        for (int nf = 0; nf < 4; ++nf) {
            int d = nf * 16 + cl;
            alv[nf] = al[head * 64 + d];
            arv[nf] = ar[head * 64 + d];
        }
        #pragma unroll
        for (int mf = 0; mf < 4; ++mf) {
            #pragma unroll
            for (int r = 0; r < 4; ++r) {
                float pl = 0.f, pr = 0.f;
                #pragma unroll
                for (int nf = 0; nf < 4; ++nf) {
                    pl += acc[mf][nf][r] * alv[nf];
                    pr += acc[mf][nf][r] * arv[nf];
                }
                #pragma unroll
                for (int msk = 1; msk <= 8; msk <<= 1) {
                    pl += __shfl_xor(pl, msk);
                    pr += __shfl_xor(pr, msk);
                }
                if (cl == 0) {
                    int gr = row0 + wm * 64 + mf * 16 + kq * 4 + r;
                    if (gr < NN) {
                        el[gr * HEADS + head] = pl;
                        er[gr * HEADS + head] = pr;
                    }
                }
            }
        }
    }
}

// ---- layer-2 scores from bf16 feat (D=41, HD=164) --------------------------
__global__ __launch_bounds__(256) void scores2_bf(
    const ushort_t* __restrict__ featb, const float* __restrict__ al,
    const float* __restrict__ ar, float* __restrict__ el, float* __restrict__ er)
{
    const int n = blockIdx.x;
    const int t = threadIdx.x;
    const int h = t >> 6;
    const int j = t & 63;
    float v = 0.f, u = 0.f;
    if (j < 41) {
        float f = bf2f(featb[(size_t)n * 164 + h * 41 + j]);
        v = f * al[h * 41 + j];
        u = f * ar[h * 41 + j];
    }
    #pragma unroll
    for (int off = 32; off > 0; off >>= 1) {
        v += __shfl_down(v, off);
        u += __shfl_down(u, off);
    }
    if (j == 0) {
        el[n * HEADS + h] = v;
        er[n * HEADS + h] = u;
    }
}

// ---- aggregation (HD=256): wave per node; writes h as hi/lo split ----------
__global__ __launch_bounds__(256) void agg_full_bf(
    const ushort_t* __restrict__ featb, const float* __restrict__ el,
    const float* __restrict__ er, const int* __restrict__ col,
    ushort_t* __restrict__ Hhi, ushort_t* __restrict__ Hlo)
{
    __shared__ int   s_src[4][DEG];
    __shared__ float s_alpha[4][HEADS][DEG];

    const int t = threadIdx.x;
    const int w = t >> 6;
    const int l = t & 63;
    const int n = blockIdx.x * 4 + w;
    const int h = l >> 4;
    const int k = l & 15;

    const int src_k = col[n * DEG + k];
    float x = el[src_k * HEADS + h] + er[n * HEADS + h];
    x = x > 0.f ? x : NEG_SLOPE * x;

    float m = x;
    #pragma unroll
    for (int msk = 8; msk >= 1; msk >>= 1) m = fmaxf(m, __shfl_xor(m, msk));
    float ex = __expf(x - m);
    float s = ex;
    #pragma unroll
    for (int msk = 8; msk >= 1; msk >>= 1) s += __shfl_xor(s, msk);

    s_alpha[w][h][k] = ex / s;
    if (l < DEG) s_src[w][l] = src_k;
    __syncthreads();

    float4 acc = make_float4(0.f, 0.f, 0.f, 0.f);
    #pragma unroll
    for (int k2 = 0; k2 < DEG; ++k2) {
        const int   sk = s_src[w][k2];
        const float a  = s_alpha[w][h][k2];
        ushort4 f = *reinterpret_cast<const ushort4*>(&featb[(size_t)sk * 256 + l * 4]);
        acc.x += a * bf2f(f.x);
        acc.y += a * bf2f(f.y);
        acc.z += a * bf2f(f.z);
        acc.w += a * bf2f(f.w);
    }
    uint32_t bx = __float_as_uint(acc.x), by = __float_as_uint(acc.y);
    uint32_t bz = __float_as_uint(acc.z), bw = __float_as_uint(acc.w);
    ushort4 hv;
    hv.x = (ushort_t)(bx >> 16); hv.y = (ushort_t)(by >> 16);
    hv.z = (ushort_t)(bz >> 16); hv.w = (ushort_t)(bw >> 16);
    float rx = acc.x - __uint_as_float(bx & 0xffff0000u);
    float ry = acc.y - __uint_as_float(by & 0xffff0000u);
    float rz = acc.z - __uint_as_float(bz & 0xffff0000u);
    float rw = acc.w - __uint_as_float(bw & 0xffff0000u);
    ushort4 lv;
    lv.x = (ushort_t)(__float_as_uint(rx) >> 16);
    lv.y = (ushort_t)(__float_as_uint(ry) >> 16);
    lv.z = (ushort_t)(__float_as_uint(rz) >> 16);
    lv.w = (ushort_t)(__float_as_uint(rw) >> 16);
    *reinterpret_cast<ushort4*>(&Hhi[(size_t)n * 256 + l * 4]) = hv;
    *reinterpret_cast<ushort4*>(&Hlo[(size_t)n * 256 + l * 4]) = lv;
}

// ---- output-layer aggregation (HD=164, mean over heads) --------------------
__global__ __launch_bounds__(256) void agg_out_bf(
    const ushort_t* __restrict__ featb, const float* __restrict__ el,
    const float* __restrict__ er, const int* __restrict__ col,
    float* __restrict__ out)   // out: [N, 41]
{
    __shared__ int   s_src[4][DEG];
    __shared__ float s_alpha[4][HEADS][DEG];
    __shared__ float s_agg[4][164];

    const int t = threadIdx.x;
    const int w = t >> 6;
    const int l = t & 63;
    const int n = blockIdx.x * 4 + w;
    const int h = l >> 4;
    const int k = l & 15;

    const int src_k = col[n * DEG + k];
    float x = el[src_k * HEADS + h] + er[n * HEADS + h];
    x = x > 0.f ? x : NEG_SLOPE * x;

    float m = x;
    #pragma unroll
    for (int msk = 8; msk >= 1; msk >>= 1) m = fmaxf(m, __shfl_xor(m, msk));
    float ex = __expf(x - m);
    float s = ex;
    #pragma unroll
    for (int msk = 8; msk >= 1; msk >>= 1) s += __shfl_xor(s, msk);

    s_alpha[w][h][k] = ex / s;
    if (l < DEG) s_src[w][l] = src_k;
    __syncthreads();

    const int l41 = l < 41 ? l : 40;
    const int c0 = 4 * l41;
    const int h0 = (c0 + 0) / 41, h1 = (c0 + 1) / 41;
    const int h2 = (c0 + 2) / 41, h3 = (c0 + 3) / 41;

    float4 acc = make_float4(0.f, 0.f, 0.f, 0.f);
    #pragma unroll
    for (int k2 = 0; k2 < DEG; ++k2) {
        const int sk = s_src[w][k2];
        ushort4 f = *reinterpret_cast<const ushort4*>(&featb[(size_t)sk * 164 + c0]);
        acc.x += s_alpha[w][h0][k2] * bf2f(f.x);
        acc.y += s_alpha[w][h1][k2] * bf2f(f.y);
        acc.z += s_alpha[w][h2][k2] * bf2f(f.z);
        acc.w += s_alpha[w][h3][k2] * bf2f(f.w);
    }
    if (l < 41) *reinterpret_cast<float4*>(&s_agg[w][c0]) = acc;
    __syncthreads();
    if (l < 41)
        out[(size_t)n * 41 + l] =
            0.25f * (s_agg[w][l] + s_agg[w][l + 41] + s_agg[w][l + 82] + s_agg[w][l + 123]);
}

extern "C" void kernel_launch(void* const* d_in, const int* in_sizes, int n_in,
                              void* d_out, int out_size, void* d_ws, size_t ws_size,
                              hipStream_t stream)
{
    const int*   col_ind = (const int*)  d_in[1];
    const float* inputs  = (const float*)d_in[2];
    const float* W0      = (const float*)d_in[3];
    const float* al0     = (const float*)d_in[4];
    const float* ar0     = (const float*)d_in[5];
    const float* W1      = (const float*)d_in[6];
    const float* al1     = (const float*)d_in[7];
    const float* ar1     = (const float*)d_in[8];
    const float* W2      = (const float*)d_in[9];
    const float* al2     = (const float*)d_in[10];
    const float* ar2     = (const float*)d_in[11];
    float* out = (float*)d_out;

    char* ws = (char*)d_ws;
    const size_t seg = (size_t)NPAD * 256 * sizeof(ushort_t);   // 51.25 MB
    ushort_t* h_hi  = (ushort_t*)(ws);
    ushort_t* h_lo  = (ushort_t*)(ws + seg);
    ushort_t* featb = (ushort_t*)(ws + 2 * seg);
    float*    el    = (float*)(ws + 3 * seg);
    float*    er    = el + (size_t)NN * HEADS;
    ushort_t* wt    = (ushort_t*)(er + (size_t)NN * HEADS);
    ushort_t* wt0h = wt;              ushort_t* wt0l = wt + 65536;
    ushort_t* wt1h = wt + 2 * 65536;  ushort_t* wt1l = wt + 3 * 65536;
    ushort_t* wt2h = wt + 4 * 65536;  ushort_t* wt2l = wt + 5 * 65536;

    dim3 blk(256);
    dim3 gg(2, (NN + 127) / 128);
    const int waveGrid = NN / 4;

    prep_wt<<<256, blk, 0, stream>>>(W0, wt0h, wt0l, 256);
    prep_wt<<<256, blk, 0, stream>>>(W1, wt1h, wt1l, 256);
    prep_wt<<<256, blk, 0, stream>>>(W2, wt2h, wt2l, 164);

    // Layer 0: fp32 A path, fused scores
    gemm_mfma<0, true><<<gg, blk, 0, stream>>>(
        inputs, nullptr, nullptr, wt0h, wt0l, al0, ar0, featb, 256, 256, el, er);
    agg_full_bf<<<waveGrid, blk, 0, stream>>>(featb, el, er, col_ind, h_hi, h_lo);

    // Layer 1: presplit A path, fused scores
    gemm_mfma<1, true><<<gg, blk, 0, stream>>>(
        nullptr, h_hi, h_lo, wt1h, wt1l, al1, ar1, featb, 256, 256, el, er);
    agg_full_bf<<<waveGrid, blk, 0, stream>>>(featb, el, er, col_ind, h_hi, h_lo);

    // Layer 2: presplit A, no fused scores
    gemm_mfma<1, false><<<gg, blk, 0, stream>>>(
        nullptr, h_hi, h_lo, wt2h, wt2l, nullptr, nullptr, featb, 164, 164, nullptr, nullptr);
    scores2_bf<<<NN, blk, 0, stream>>>(featb, al2, ar2, el, er);
    agg_out_bf<<<waveGrid, blk, 0, stream>>>(featb, el, er, col_ind, out);
}